// Round 4
// baseline (1683.397 us; speedup 1.0000x reference)
//
#include <hip/hip_runtime.h>
#include <hip/hip_cooperative_groups.h>
#include <stdint.h>

namespace cg = cooperative_groups;

#define BB 4
#define HH 256
#define WW 256
#define CC 128
#define NN 32
#define NPIX (HH*WW)            // 65536
#define RANK 52428u             // 0-based order-stat index: 0.8*(65536-1) exactly
#define TOTAL_PAIRS 1984.0f     // B * N*(N-1)/2
#define TG 1024                 // grid blocks; TG*256 == BB*NPIX (1 thread/pixel)

// workspace byte offsets
// sm (u32): [0..3]=cand cnt, [4+b]=T(qbin), [8+b]=r2, [12+b]=thr_key(bits)
#define OFF_SM      0                         // 4 KiB
#define OFF_PART    4096                      // BB*256 u32 = 4 KiB
#define OFF_H       8192                      // BB*65536 u32 = 1 MiB
#define OFF_GSPLIT  (OFF_H + BB*65536*4)      // BB*12288 shorts = 96 KiB
#define OFF_GN      (OFF_GSPLIT + BB*12288*2) // BB*NN floats (pad 4 KiB)
#define OFF_KEYS    (OFF_GN + 4096)           // BB*NPIX u32 = 1 MiB
#define OFF_CAND    (OFF_KEYS + BB*NPIX*4)    // BB*65536 u32 = 1 MiB
#define OFF_P       (OFF_CAND + BB*65536*4)   // BB*NPIX i32 = 1 MiB

typedef __attribute__((ext_vector_type(8))) short short8;
typedef __attribute__((ext_vector_type(4))) float f32x4;

// 3-way bf16 split via truncation; residual <= 2^-24 |f| (verified round 3, absmax 0).
__device__ __forceinline__ void split3(float f, short &hi, short &mid, short &lo) {
    uint32_t u  = __float_as_uint(f);
    uint32_t hb = u & 0xffff0000u;
    hi = (short)(hb >> 16);
    float r1 = f - __uint_as_float(hb);
    uint32_t mb = __float_as_uint(r1) & 0xffff0000u;
    mid = (short)(mb >> 16);
    float r2 = r1 - __uint_as_float(mb);
    lo = (short)(__float_as_uint(r2) >> 16);
}

// quantized bin: monotone nondecreasing in d2 -> exact radix-select level 1.
// Uniform bin width 1/128 spreads the concentrated d2 distribution (low atomic contention).
__device__ __forceinline__ uint32_t qbin_of(uint32_t keybits) {
    float f = __uint_as_float(keybits);
    return (uint32_t)fminf(f * 128.0f, 65535.0f);
}

// union-find (verified round 3)
__device__ __forceinline__ int uf_find(int* P, int x) {
    while (true) {
        int p = P[x];
        if (p == x) return x;
        int gp = P[p];
        if (gp != p) P[x] = gp;   // path halving (benign race)
        x = gp;
    }
}
__device__ __forceinline__ void uf_unite(int* P, int a, int b) {
    while (true) {
        a = uf_find(P, a);
        b = uf_find(P, b);
        if (a == b) return;
        if (a > b) { int t = a; a = b; b = t; }
        int old = atomicCAS(&P[b], b, a);   // device-scope
        if (old == b) return;
        b = old;
    }
}

__global__ __launch_bounds__(256, 4) void k_mono(
        const float* __restrict__ feat, const int* __restrict__ centers,
        float* __restrict__ out, uint32_t* __restrict__ sm, uint32_t* __restrict__ part,
        uint32_t* __restrict__ h, short* __restrict__ gsplit, float* __restrict__ gnorm,
        uint32_t* __restrict__ keys, uint32_t* __restrict__ cand, int* __restrict__ Pg) {
    cg::grid_group grid = cg::this_grid();
    __shared__ short gB[12288];   // 24 KiB; aliased by later phases
    const int g = blockIdx.x, t = threadIdx.x;
    const int gi = g*256 + t;     // global thread id, 0..262143 == BB*NPIX

    // ---- phase Z: zero h + sm (ws is poisoned 0xAA each call) ----
    h[gi] = 0;                    // exactly BB*65536 entries
    if (g == 0 && t < 64) sm[t] = 0;

    // ---- phase G: gather center features -> split B-fragments + |g|^2 ----
    if (g < BB*NN) {
        int b = g >> 5, n = g & 31;
        float v = 0.f;
        float* sred = (float*)gB;
        if (t < CC) {
            int cy = centers[(b*NN + n)*2 + 0];
            int cx = centers[(b*NN + n)*2 + 1];
            v = feat[((size_t)(b << 16) + cy*WW + cx)*CC + t];
            short hi, mid, lo; split3(v, hi, mid, lo);
            int tt = n >> 4, kk = t >> 5, q = (t & 31) >> 3, j = t & 7;
            int lane = q*16 + (n & 15);
            size_t base = (size_t)b*12288 + (size_t)(tt*4 + kk)*512 + lane*8 + j;
            gsplit[base]        = hi;
            gsplit[base + 4096] = mid;
            gsplit[base + 8192] = lo;
        }
        sred[t] = v*v;
        __syncthreads();
        for (int off = 128; off > 0; off >>= 1) {
            if (t < off) sred[t] += sred[t + off];
            __syncthreads();
        }
        if (t == 0) gnorm[b*NN + n] = sred[0];
    }
    __threadfence();
    grid.sync();

    // ---- phase M: MFMA min-distance + keys + quantized histogram ----
    {
        int wv = t >> 6, L = t & 63;
        int m = L & 15, q = L >> 4;
        for (int u = g; u < BB*1024; u += TG) {   // exactly 4 uniform iterations
            int b = u >> 10, tile = u & 1023;
            __syncthreads();
            {   // stage pre-split G fragments (1536 uint4 block copy)
                const uint4* src = (const uint4*)(gsplit + (size_t)b*12288);
                uint4* dst = (uint4*)gB;
                #pragma unroll
                for (int i = 0; i < 6; i++) dst[t + i*256] = src[t + i*256];
            }
            __syncthreads();

            int p0 = tile*64 + wv*16;
            const float* fp = feat + ((size_t)(b << 16) + p0 + m)*CC + q*8;

            f32x4 acc[2] = {{0.f,0.f,0.f,0.f},{0.f,0.f,0.f,0.f}};
            float fn = 0.f;
            #pragma unroll
            for (int kk = 0; kk < 4; kk++) {
                float4 fa = *(const float4*)(fp + kk*32);
                float4 fb = *(const float4*)(fp + kk*32 + 4);
                float fs[8] = {fa.x,fa.y,fa.z,fa.w,fb.x,fb.y,fb.z,fb.w};
                short8 ahi, amid, alo;
                #pragma unroll
                for (int j = 0; j < 8; j++) {
                    float f = fs[j];
                    fn = fmaf(f, f, fn);
                    short hh, md, lw; split3(f, hh, md, lw);
                    ahi[j] = hh; amid[j] = md; alo[j] = lw;
                }
                #pragma unroll
                for (int tt = 0; tt < 2; tt++) {
                    int off = (tt*4 + kk)*512 + L*8;
                    short8 bhi = *(const short8*)&gB[off];
                    short8 bmd = *(const short8*)&gB[off + 4096];
                    short8 blo = *(const short8*)&gB[off + 8192];
                    acc[tt] = __builtin_amdgcn_mfma_f32_16x16x32_bf16(ahi,  bhi, acc[tt], 0,0,0);
                    acc[tt] = __builtin_amdgcn_mfma_f32_16x16x32_bf16(ahi,  bmd, acc[tt], 0,0,0);
                    acc[tt] = __builtin_amdgcn_mfma_f32_16x16x32_bf16(amid, bhi, acc[tt], 0,0,0);
                    acc[tt] = __builtin_amdgcn_mfma_f32_16x16x32_bf16(ahi,  blo, acc[tt], 0,0,0);
                    acc[tt] = __builtin_amdgcn_mfma_f32_16x16x32_bf16(amid, bmd, acc[tt], 0,0,0);
                    acc[tt] = __builtin_amdgcn_mfma_f32_16x16x32_bf16(alo,  bhi, acc[tt], 0,0,0);
                }
            }
            fn += __shfl_xor(fn, 16);
            fn += __shfl_xor(fn, 32);
            float gn0 = gnorm[b*NN + m];
            float gn1 = gnorm[b*NN + 16 + m];
            float vmin[4];
            #pragma unroll
            for (int r = 0; r < 4; r++) {
                float fnr = __shfl(fn, q*4 + r);
                float d0 = fnr + gn0 - 2.f*acc[0][r];
                float d1 = fnr + gn1 - 2.f*acc[1][r];
                float v = fminf(d0, d1);
                v = fminf(v, __shfl_xor(v, 1));
                v = fminf(v, __shfl_xor(v, 2));
                v = fminf(v, __shfl_xor(v, 4));
                v = fminf(v, __shfl_xor(v, 8));
                vmin[r] = v;
            }
            if (m < 4) {
                float v = (m==0) ? vmin[0] : (m==1) ? vmin[1] : (m==2) ? vmin[2] : vmin[3];
                if (!(v > 0.f)) v = 0.f;
                uint32_t key = __float_as_uint(v);
                int pix = p0 + q*4 + m;
                keys[(size_t)(b << 16) + pix] = key;
                atomicAdd(&h[(b << 16) + qbin_of(key)], 1u);
            }
        }
    }
    __threadfence();
    grid.sync();

    // ---- phase A1: per-wave segment sums of h (1024 segments of 256 bins) ----
    {
        int w = g*4 + (t >> 6), L = t & 63;
        if (w < BB*256) {
            int b = w >> 8, seg = w & 255;
            const uint4* h4 = (const uint4*)(h + (b << 16) + seg*256);
            uint4 v = h4[L];
            uint32_t s = v.x + v.y + v.z + v.w;
            #pragma unroll
            for (int off = 1; off < 64; off <<= 1) s += __shfl_xor((int)s, off);
            if (L == 0) part[b*256 + seg] = s;
        }
    }
    __threadfence();
    grid.sync();

    // ---- phase A2: select bin T containing RANK + rank-within-bin r2 ----
    if (g < BB) {
        int b = g;
        uint32_t* seg = (uint32_t*)gB;
        uint32_t* pre = seg + 256;
        seg[t] = part[b*256 + t];
        __syncthreads();
        if (t == 0) { uint32_t c = 0; for (int i = 0; i < 256; i++) { pre[i] = c; c += seg[i]; } }
        __syncthreads();
        uint32_t r = RANK;
        if (pre[t] <= r && r < pre[t] + seg[t]) {
            uint32_t c = pre[t];
            const uint32_t* hb = h + (b << 16) + t*256;
            for (int i = 0; i < 256; i++) {
                uint32_t hc = hb[i];
                if (r < c + hc) { sm[4 + b] = (uint32_t)(t*256 + i); sm[8 + b] = r - c; break; }
                c += hc;
            }
        }
    }
    __threadfence();
    grid.sync();

    // ---- phase B: collect candidate keys in bin T (expected ~5/batch) ----
    {
        int b = gi >> 16;
        uint32_t key = keys[gi];
        if (qbin_of(key) == sm[4 + b]) {
            uint32_t pos = atomicAdd(&sm[b], 1u);
            if (pos < 65536u) cand[(b << 16) + pos] = key;
        }
    }
    __threadfence();
    grid.sync();

    // ---- phase C: exact rank among candidates -> threshold key bits ----
    if (g < BB) {
        int b = g;
        uint32_t K = sm[b]; if (K > 65536u) K = 65536u;
        uint32_t r2 = sm[8 + b];
        const uint32_t* cb = cand + (b << 16);
        for (uint32_t i = t; i < K; i += 256) {
            uint32_t v = cb[i];
            uint32_t less = 0, eq = 0;
            for (uint32_t j = 0; j < K; j++) { uint32_t w = cb[j]; less += (w < v); eq += (w == v); }
            if (less <= r2 && r2 < less + eq) sm[12 + b] = v;   // all writers agree
        }
    }
    __threadfence();
    grid.sync();

    // ---- phase D: init union-find parents from mask ----
    {
        int b = gi >> 16, p = gi & 65535;
        Pg[gi] = (keys[gi] >= sm[12 + b]) ? p : -1;   // uint cmp == float cmp (keys >= +0)
    }
    __threadfence();
    grid.sync();

    // ---- phase E: 8-connected union-find CCL ----
    {
        int b = gi >> 16, p = gi & 65535;
        int* P = Pg + (b << 16);
        if (P[p] != -1) {
            int y = p >> 8, x = p & 255;
            if (x > 0      && P[p-1]      != -1) uf_unite(P, p, p-1);
            if (y > 0) {
                if (          P[p-WW]     != -1) uf_unite(P, p, p-WW);
                if (x > 0  && P[p-WW-1]   != -1) uf_unite(P, p, p-WW-1);
                if (x < WW-1 && P[p-WW+1] != -1) uf_unite(P, p, p-WW+1);
            }
        }
    }
    __threadfence();
    grid.sync();

    // ---- phase F: merged pairs at centers + output ----
    if (g == 0) {
        int* ids = (int*)gB;
        int* tot = ids + 128;
        if (t == 0) *tot = 0;
        if (t < BB*NN) {
            int b = t >> 5;
            int cy = centers[t*2 + 0];
            int cx = centers[t*2 + 1];
            int p = cy*WW + cx;
            int* P = Pg + (b << 16);
            int id = atomicAdd(&P[p], 0);          // coherent read
            if (id != -1) {
                int x = p;
                while (true) { int q = atomicAdd(&P[x], 0); if (q == x) break; x = q; }
                id = x;
            }
            ids[t] = id;
        }
        __syncthreads();
        int cnt = 0;
        if (t < BB*NN) {
            int b = t >> 5, n = t & 31;
            int id = ids[t];
            if (id != -1) for (int j = n+1; j < NN; j++) cnt += (ids[b*NN + j] == id);
        }
        if (cnt) atomicAdd(tot, cnt);
        __syncthreads();
        if (t == 0) out[0] = (float)(*tot) / TOTAL_PAIRS;
    }
}

extern "C" void kernel_launch(void* const* d_in, const int* in_sizes, int n_in,
                              void* d_out, int out_size, void* d_ws, size_t ws_size,
                              hipStream_t stream) {
    const float* feat  = (const float*)d_in[0];
    const int* centers = (const int*)d_in[1];
    float* out         = (float*)d_out;
    char* ws           = (char*)d_ws;

    uint32_t* sm     = (uint32_t*)(ws + OFF_SM);
    uint32_t* part   = (uint32_t*)(ws + OFF_PART);
    uint32_t* h      = (uint32_t*)(ws + OFF_H);
    short*    gsplit = (short*)(ws + OFF_GSPLIT);
    float*    gnorm  = (float*)(ws + OFF_GN);
    uint32_t* keys   = (uint32_t*)(ws + OFF_KEYS);
    uint32_t* cand   = (uint32_t*)(ws + OFF_CAND);
    int*      Pg     = (int*)(ws + OFF_P);

    void* args[] = {(void*)&feat, (void*)&centers, (void*)&out, (void*)&sm, (void*)&part,
                    (void*)&h, (void*)&gsplit, (void*)&gnorm, (void*)&keys, (void*)&cand,
                    (void*)&Pg};
    hipLaunchCooperativeKernel((void*)k_mono, dim3(TG), dim3(256), args, 0, stream);
}

// Round 5
// 253.002 us; speedup vs baseline: 6.6537x; 6.6537x over previous
//
#include <hip/hip_runtime.h>
#include <stdint.h>

#define BB 4
#define HH 256
#define WW 256
#define CC 128
#define NN 32
#define NPIX (HH*WW)            // 65536
#define RANK 52428u             // 0-based order-stat index: 0.8*(65536-1) exactly
#define TOTAL_PAIRS 1984.0f     // B * N*(N-1)/2

// workspace byte offsets
// sm (u32): [0..3]=cand cnt, [4+b]=T(qbin), [8+b]=r2, [12+b]=thr_key(bits)
#define OFF_SM      0                         // 4 KiB
#define OFF_H       4096                      // BB*65536 u32 = 1 MiB
#define OFF_GSPLIT  (OFF_H + BB*65536*4)      // BB*12288 shorts = 96 KiB
#define OFF_GN      (OFF_GSPLIT + BB*12288*2) // BB*NN floats (pad 4 KiB)
#define OFF_KEYS    (OFF_GN + 4096)           // BB*NPIX u32 = 1 MiB
#define OFF_CAND    (OFF_KEYS + BB*NPIX*4)    // BB*65536 u32 = 1 MiB
#define OFF_P       (OFF_CAND + BB*65536*4)   // BB*NPIX i32 = 1 MiB

typedef __attribute__((ext_vector_type(8))) short short8;
typedef __attribute__((ext_vector_type(4))) float f32x4;

// 3-way bf16 split via truncation; residual <= 2^-24 |f| (absmax 0 in rounds 3-4).
__device__ __forceinline__ void split3(float f, short &hi, short &mid, short &lo) {
    uint32_t u  = __float_as_uint(f);
    uint32_t hb = u & 0xffff0000u;
    hi = (short)(hb >> 16);
    float r1 = f - __uint_as_float(hb);
    uint32_t mb = __float_as_uint(r1) & 0xffff0000u;
    mid = (short)(mb >> 16);
    float r2 = r1 - __uint_as_float(mb);
    lo = (short)(__float_as_uint(r2) >> 16);
}

// quantized bin: monotone nondecreasing in d2 (x128 is exact pow2 scale) -> exact select.
// Uniform width spreads the concentrated d2 distribution => low atomic contention.
__device__ __forceinline__ uint32_t qbin_of(uint32_t keybits) {
    float f = __uint_as_float(keybits);
    return (uint32_t)fminf(f * 128.0f, 65535.0f);
}

// ---------------- K0: gather center features -> split B-fragments + |g|^2; zero h/sm ----
__global__ void k_gather(const float* __restrict__ feat, const int* __restrict__ centers,
                         short* __restrict__ gsplit, float* __restrict__ gnorm,
                         uint32_t* __restrict__ h, uint32_t* __restrict__ sm) {
    int g = blockIdx.x;           // 128 blocks
    int b = g >> 5, n = g & 31;
    int c = threadIdx.x;          // 128 threads

    // zero histogram (1 MiB) + sm: 16384 threads x 4 uint4
    {
        uint4* h4 = (uint4*)h;
        int zi = g*128 + c;
        #pragma unroll
        for (int i = 0; i < 4; i++) h4[zi + i*16384] = make_uint4(0,0,0,0);
        if (g == 0 && c < 64) sm[c] = 0;
    }

    int cy = centers[(b*NN + n)*2 + 0];
    int cx = centers[(b*NN + n)*2 + 1];
    float v = feat[((size_t)(b << 16) + cy*WW + cx)*CC + c];
    short hi, mid, lo; split3(v, hi, mid, lo);
    int tt = n >> 4, kk = c >> 5, q = (c & 31) >> 3, j = c & 7;
    int lane = q*16 + (n & 15);
    size_t base = (size_t)b*12288 + (size_t)(tt*4 + kk)*512 + lane*8 + j;
    gsplit[base]        = hi;
    gsplit[base + 4096] = mid;
    gsplit[base + 8192] = lo;

    __shared__ float s[128];
    s[c] = v*v;
    __syncthreads();
    for (int off = 64; off > 0; off >>= 1) {
        if (c < off) s[c] += s[c+off];
        __syncthreads();
    }
    if (c == 0) gnorm[b*NN + n] = s[0];
}

// ---------------- K1: MFMA min squared distance -> keys (no atomics) ----------------
// block = 256 threads = 4 waves; wave handles 16 pixels; block 64 pixels.
__global__ __launch_bounds__(256) void k_d2mfma(const float* __restrict__ feat,
        const short* __restrict__ gsplit, const float* __restrict__ gnorm,
        uint32_t* __restrict__ keys) {
    __shared__ short gB[12288];   // 24 KiB: [s][t*4+kk][lane][8]
    int b = blockIdx.y;

    {   // stage pre-split G fragments (coalesced 1536 uint4)
        const uint4* src = (const uint4*)(gsplit + (size_t)b*12288);
        uint4* dst = (uint4*)gB;
        #pragma unroll
        for (int i = 0; i < 6; i++) dst[threadIdx.x + i*256] = src[threadIdx.x + i*256];
    }
    __syncthreads();

    int wv = threadIdx.x >> 6, L = threadIdx.x & 63;
    int m = L & 15, q = L >> 4;
    int p0 = blockIdx.x*64 + wv*16;
    const float* fp = feat + ((size_t)(b << 16) + p0 + m)*CC + q*8;

    f32x4 acc[2] = {{0.f,0.f,0.f,0.f},{0.f,0.f,0.f,0.f}};
    float fn = 0.f;

    #pragma unroll
    for (int kk = 0; kk < 4; kk++) {
        float4 fa = *(const float4*)(fp + kk*32);
        float4 fb = *(const float4*)(fp + kk*32 + 4);
        float fs[8] = {fa.x,fa.y,fa.z,fa.w,fb.x,fb.y,fb.z,fb.w};
        short8 ahi, amid, alo;
        #pragma unroll
        for (int j = 0; j < 8; j++) {
            float f = fs[j];
            fn = fmaf(f, f, fn);
            short h, md, lw; split3(f, h, md, lw);
            ahi[j] = h; amid[j] = md; alo[j] = lw;
        }
        #pragma unroll
        for (int t = 0; t < 2; t++) {
            int off = (t*4 + kk)*512 + L*8;
            short8 bhi = *(const short8*)&gB[off];
            short8 bmd = *(const short8*)&gB[off + 4096];
            short8 blo = *(const short8*)&gB[off + 8192];
            // 6 significant split products
            acc[t] = __builtin_amdgcn_mfma_f32_16x16x32_bf16(ahi,  bhi, acc[t], 0,0,0);
            acc[t] = __builtin_amdgcn_mfma_f32_16x16x32_bf16(ahi,  bmd, acc[t], 0,0,0);
            acc[t] = __builtin_amdgcn_mfma_f32_16x16x32_bf16(amid, bhi, acc[t], 0,0,0);
            acc[t] = __builtin_amdgcn_mfma_f32_16x16x32_bf16(ahi,  blo, acc[t], 0,0,0);
            acc[t] = __builtin_amdgcn_mfma_f32_16x16x32_bf16(amid, bmd, acc[t], 0,0,0);
            acc[t] = __builtin_amdgcn_mfma_f32_16x16x32_bf16(alo,  bhi, acc[t], 0,0,0);
        }
    }

    fn += __shfl_xor(fn, 16);
    fn += __shfl_xor(fn, 32);
    float gn0 = gnorm[b*NN + m];
    float gn1 = gnorm[b*NN + 16 + m];

    // C layout: col(n) = L&15, row(pixel) = q*4 + reg
    float vmin[4];
    #pragma unroll
    for (int r = 0; r < 4; r++) {
        float fnr = __shfl(fn, q*4 + r);
        float d0 = fnr + gn0 - 2.f*acc[0][r];
        float d1 = fnr + gn1 - 2.f*acc[1][r];
        float v = fminf(d0, d1);
        v = fminf(v, __shfl_xor(v, 1));
        v = fminf(v, __shfl_xor(v, 2));
        v = fminf(v, __shfl_xor(v, 4));
        v = fminf(v, __shfl_xor(v, 8));
        vmin[r] = v;
    }
    if (m < 4) {
        float v = (m==0) ? vmin[0] : (m==1) ? vmin[1] : (m==2) ? vmin[2] : vmin[3];
        if (!(v > 0.f)) v = 0.f;     // clamp negatives and -0.0
        keys[(size_t)(b << 16) + p0 + q*4 + m] = __float_as_uint(v);
    }
}

// ---------------- K2: quantized histogram (spread bins -> low contention) ----------------
__global__ __launch_bounds__(256) void k_histq(const uint32_t* __restrict__ keys,
                                               uint32_t* __restrict__ h) {
    int b = blockIdx.y;
    int p = blockIdx.x*256 + threadIdx.x;
    uint32_t k = keys[(b << 16) + p];
    atomicAdd(&h[(b << 16) + qbin_of(k)], 1u);
}

// ---------------- K3: scan 65536 bins for RANK -> qbin T, within-bin rank r2 ----------------
__global__ __launch_bounds__(1024) void k_selq(const uint32_t* __restrict__ h,
                                               uint32_t* __restrict__ sm) {
    int b = blockIdx.x, t = threadIdx.x;   // 1024 threads, 64 bins each
    __shared__ uint32_t seg[1024];
    __shared__ uint32_t pre[1024];
    const uint4* h4 = (const uint4*)(h + (b << 16) + t*64);
    uint32_t s = 0;
    #pragma unroll
    for (int i = 0; i < 16; i++) { uint4 v = h4[i]; s += v.x + v.y + v.z + v.w; }
    seg[t] = s;
    __syncthreads();
    if (t == 0) { uint32_t c = 0; for (int i = 0; i < 1024; i++) { pre[i] = c; c += seg[i]; } }
    __syncthreads();
    uint32_t r = RANK;
    if (pre[t] <= r && r < pre[t] + seg[t]) {
        uint32_t c = pre[t];
        const uint32_t* hb = h + (b << 16) + t*64;
        for (int i = 0; i < 64; i++) {
            uint32_t hc = hb[i];
            if (r < c + hc) { sm[4 + b] = (uint32_t)(t*64 + i); sm[8 + b] = r - c; break; }
            c += hc;
        }
    }
}

// ---------------- K4: collect candidate keys in bin T (~30/batch) ----------------
__global__ __launch_bounds__(256) void k_collect(const uint32_t* __restrict__ keys,
        uint32_t* __restrict__ sm, uint32_t* __restrict__ cand) {
    int b = blockIdx.y;
    int p = blockIdx.x*256 + threadIdx.x;
    uint32_t k = keys[(b << 16) + p];
    if (qbin_of(k) == sm[4 + b]) {
        uint32_t pos = atomicAdd(&sm[b], 1u);
        if (pos < 65536u) cand[(b << 16) + pos] = k;
    }
}

// ---------------- K5: exact rank among candidates -> threshold key bits ----------------
__global__ void k_rank(const uint32_t* __restrict__ cand, uint32_t* __restrict__ sm) {
    int b = blockIdx.x, t = threadIdx.x;   // 256 threads
    uint32_t K = sm[b]; if (K > 65536u) K = 65536u;
    uint32_t r2 = sm[8 + b];
    const uint32_t* cb = cand + (b << 16);
    for (uint32_t i = t; i < K; i += 256) {
        uint32_t v = cb[i];
        uint32_t less = 0, eq = 0;
        for (uint32_t j = 0; j < K; j++) { uint32_t w = cb[j]; less += (w < v); eq += (w == v); }
        if (less <= r2 && r2 < less + eq) sm[12 + b] = v;   // all writers agree
    }
}

// ---------------- K6: init union-find parents from mask ----------------
__global__ __launch_bounds__(256) void k_initp(const uint32_t* __restrict__ keys,
        const uint32_t* __restrict__ sm, int* __restrict__ P) {
    int b = blockIdx.y;
    int p = blockIdx.x*256 + threadIdx.x;
    P[(b << 16) + p] = (keys[(b << 16) + p] >= sm[12 + b]) ? p : -1;
}

// ---------------- K7: union-find CCL (8-connected) ----------------
__device__ __forceinline__ int uf_find(int* P, int x) {
    while (true) {
        int p = P[x];
        if (p == x) return x;
        int gp = P[p];
        if (gp != p) P[x] = gp;   // path halving (benign race)
        x = gp;
    }
}
__device__ __forceinline__ void uf_unite(int* P, int a, int b) {
    while (true) {
        a = uf_find(P, a);
        b = uf_find(P, b);
        if (a == b) return;
        if (a > b) { int t = a; a = b; b = t; }
        int old = atomicCAS(&P[b], b, a);   // device-scope
        if (old == b) return;
        b = old;
    }
}
__global__ __launch_bounds__(256) void k_union(int* __restrict__ Pg) {
    int b = blockIdx.y;
    int p = blockIdx.x*256 + threadIdx.x;
    int* P = Pg + (b << 16);
    if (P[p] == -1) return;
    int y = p >> 8, x = p & 255;
    if (x > 0      && P[p-1]      != -1) uf_unite(P, p, p-1);
    if (y > 0) {
        if (          P[p-WW]     != -1) uf_unite(P, p, p-WW);
        if (x > 0  && P[p-WW-1]   != -1) uf_unite(P, p, p-WW-1);
        if (x < WW-1 && P[p-WW+1] != -1) uf_unite(P, p, p-WW+1);
    }
}

// ---------------- K8: merged pairs at centers + output ----------------
__global__ void k_pairs_fin(const int* __restrict__ centers, int* __restrict__ Pg,
                            float* __restrict__ out) {
    __shared__ int ids[BB*NN];
    __shared__ int total;
    int t = threadIdx.x;
    if (t == 0) total = 0;
    __syncthreads();
    if (t < BB*NN) {
        int b = t >> 5;
        int cy = centers[t*2 + 0];
        int cx = centers[t*2 + 1];
        int p = cy*WW + cx;
        const int* P = Pg + (b << 16);
        int id = P[p];
        if (id != -1) {
            int x = p;
            while (true) { int q = P[x]; if (q == x) break; x = q; }
            id = x;
        }
        ids[t] = id;
    }
    __syncthreads();
    int cnt = 0;
    if (t < BB*NN) {
        int b = t >> 5, n = t & 31;
        int id = ids[t];
        if (id != -1) for (int j = n+1; j < NN; j++) cnt += (ids[b*NN + j] == id);
    }
    if (cnt) atomicAdd(&total, cnt);
    __syncthreads();
    if (t == 0) out[0] = (float)total / TOTAL_PAIRS;
}

extern "C" void kernel_launch(void* const* d_in, const int* in_sizes, int n_in,
                              void* d_out, int out_size, void* d_ws, size_t ws_size,
                              hipStream_t stream) {
    const float* feat  = (const float*)d_in[0];
    const int* centers = (const int*)d_in[1];
    float* out         = (float*)d_out;
    char* ws           = (char*)d_ws;

    uint32_t* sm     = (uint32_t*)(ws + OFF_SM);
    uint32_t* h      = (uint32_t*)(ws + OFF_H);
    short*    gsplit = (short*)(ws + OFF_GSPLIT);
    float*    gnorm  = (float*)(ws + OFF_GN);
    uint32_t* keys   = (uint32_t*)(ws + OFF_KEYS);
    uint32_t* cand   = (uint32_t*)(ws + OFF_CAND);
    int*      Pg     = (int*)(ws + OFF_P);

    dim3 gridPix(NPIX/256, BB);
    dim3 gridMM(NPIX/64, BB);

    k_gather    <<<BB*NN, CC, 0, stream>>>(feat, centers, gsplit, gnorm, h, sm);
    k_d2mfma    <<<gridMM, 256, 0, stream>>>(feat, gsplit, gnorm, keys);
    k_histq     <<<gridPix, 256, 0, stream>>>(keys, h);
    k_selq      <<<BB, 1024, 0, stream>>>(h, sm);
    k_collect   <<<gridPix, 256, 0, stream>>>(keys, sm, cand);
    k_rank      <<<BB, 256, 0, stream>>>(cand, sm);
    k_initp     <<<gridPix, 256, 0, stream>>>(keys, sm, Pg);
    k_union     <<<gridPix, 256, 0, stream>>>(Pg);
    k_pairs_fin <<<1, 256, 0, stream>>>(centers, Pg, out);
}

// Round 6
// 244.492 us; speedup vs baseline: 6.8853x; 1.0348x over previous
//
#include <hip/hip_runtime.h>
#include <stdint.h>

#define BB 4
#define HH 256
#define WW 256
#define CC 128
#define NN 32
#define NPIX (HH*WW)            // 65536
#define RANK 52428u             // 0-based order-stat index: 0.8*(65536-1) exactly
#define TOTAL_PAIRS 1984.0f     // B * N*(N-1)/2

// workspace byte offsets
// sm (u32): [0..3]=cand cnt, [4+b]=T(qbin), [8+b]=r2, [12+b]=thr_key(bits)
#define OFF_SM      0                         // 4 KiB
#define OFF_H       4096                      // BB*65536 u32 = 1 MiB
#define OFF_GSPLIT  (OFF_H + BB*65536*4)      // BB*12288 shorts = 96 KiB
#define OFF_GN      (OFF_GSPLIT + BB*12288*2) // BB*NN floats (pad 4 KiB)
#define OFF_KEYS    (OFF_GN + 4096)           // BB*NPIX u32 = 1 MiB
#define OFF_CAND    (OFF_KEYS + BB*NPIX*4)    // BB*65536 u32 = 1 MiB
#define OFF_P       (OFF_CAND + BB*65536*4)   // BB*NPIX i32 = 1 MiB

typedef __attribute__((ext_vector_type(8))) short short8;
typedef __attribute__((ext_vector_type(4))) float f32x4;

// 3-way bf16 split via truncation; residual <= 2^-24 |f| (absmax 0 in rounds 3-5).
__device__ __forceinline__ void split3(float f, short &hi, short &mid, short &lo) {
    uint32_t u  = __float_as_uint(f);
    uint32_t hb = u & 0xffff0000u;
    hi = (short)(hb >> 16);
    float r1 = f - __uint_as_float(hb);
    uint32_t mb = __float_as_uint(r1) & 0xffff0000u;
    mid = (short)(mb >> 16);
    float r2 = r1 - __uint_as_float(mb);
    lo = (short)(__float_as_uint(r2) >> 16);
}

// quantized bin: monotone nondecreasing in d2 (x128 exact pow2 scale) -> exact select.
// Uniform width spreads the concentrated d2 distribution => ~5-15 keys/bin (low contention).
__device__ __forceinline__ uint32_t qbin_of(uint32_t keybits) {
    float f = __uint_as_float(keybits);
    return (uint32_t)fminf(f * 128.0f, 65535.0f);
}

// ---------------- K0: gather center features -> split B-fragments + |g|^2; zero h/sm ----
__global__ void k_gather(const float* __restrict__ feat, const int* __restrict__ centers,
                         short* __restrict__ gsplit, float* __restrict__ gnorm,
                         uint32_t* __restrict__ h, uint32_t* __restrict__ sm) {
    int g = blockIdx.x;           // 128 blocks
    int b = g >> 5, n = g & 31;
    int c = threadIdx.x;          // 128 threads

    // zero histogram (1 MiB) + sm: 16384 threads x 4 uint4
    {
        uint4* h4 = (uint4*)h;
        int zi = g*128 + c;
        #pragma unroll
        for (int i = 0; i < 4; i++) h4[zi + i*16384] = make_uint4(0,0,0,0);
        if (g == 0 && c < 64) sm[c] = 0;
    }

    int cy = centers[(b*NN + n)*2 + 0];
    int cx = centers[(b*NN + n)*2 + 1];
    float v = feat[((size_t)(b << 16) + cy*WW + cx)*CC + c];
    short hi, mid, lo; split3(v, hi, mid, lo);
    int tt = n >> 4, kk = c >> 5, q = (c & 31) >> 3, j = c & 7;
    int lane = q*16 + (n & 15);
    size_t base = (size_t)b*12288 + (size_t)(tt*4 + kk)*512 + lane*8 + j;
    gsplit[base]        = hi;
    gsplit[base + 4096] = mid;
    gsplit[base + 8192] = lo;

    __shared__ float s[128];
    s[c] = v*v;
    __syncthreads();
    for (int off = 64; off > 0; off >>= 1) {
        if (c < off) s[c] += s[c+off];
        __syncthreads();
    }
    if (c == 0) gnorm[b*NN + n] = s[0];
}

// ---------------- K1: MFMA min squared distance -> keys + fused quantized histogram ------
// block = 256 threads = 4 waves; each wave loops 4 tiles of 16 pixels => 256 px/block.
__global__ __launch_bounds__(256) void k_d2mfma(const float* __restrict__ feat,
        const short* __restrict__ gsplit, const float* __restrict__ gnorm,
        uint32_t* __restrict__ keys, uint32_t* __restrict__ h) {
    __shared__ short gB[12288];   // 24 KiB: [s][t*4+kk][lane][8]
    int b = blockIdx.y;

    {   // stage pre-split G fragments once per block (coalesced 1536 uint4)
        const uint4* src = (const uint4*)(gsplit + (size_t)b*12288);
        uint4* dst = (uint4*)gB;
        #pragma unroll
        for (int i = 0; i < 6; i++) dst[threadIdx.x + i*256] = src[threadIdx.x + i*256];
    }
    __syncthreads();

    int wv = threadIdx.x >> 6, L = threadIdx.x & 63;
    int m = L & 15, q = L >> 4;
    float gn0 = gnorm[b*NN + m];          // hoisted: depend on m only
    float gn1 = gnorm[b*NN + 16 + m];

    for (int it = 0; it < 4; it++) {
        int p0 = blockIdx.x*256 + (wv*4 + it)*16;
        const float* fp = feat + ((size_t)(b << 16) + p0 + m)*CC + q*8;

        f32x4 acc[2] = {{0.f,0.f,0.f,0.f},{0.f,0.f,0.f,0.f}};
        float fn = 0.f;

        #pragma unroll
        for (int kk = 0; kk < 4; kk++) {
            float4 fa = *(const float4*)(fp + kk*32);
            float4 fb = *(const float4*)(fp + kk*32 + 4);
            float fs[8] = {fa.x,fa.y,fa.z,fa.w,fb.x,fb.y,fb.z,fb.w};
            short8 ahi, amid, alo;
            #pragma unroll
            for (int j = 0; j < 8; j++) {
                float f = fs[j];
                fn = fmaf(f, f, fn);
                short hh, md, lw; split3(f, hh, md, lw);
                ahi[j] = hh; amid[j] = md; alo[j] = lw;
            }
            #pragma unroll
            for (int t = 0; t < 2; t++) {
                int off = (t*4 + kk)*512 + L*8;
                short8 bhi = *(const short8*)&gB[off];
                short8 bmd = *(const short8*)&gB[off + 4096];
                short8 blo = *(const short8*)&gB[off + 8192];
                // 6 significant split products
                acc[t] = __builtin_amdgcn_mfma_f32_16x16x32_bf16(ahi,  bhi, acc[t], 0,0,0);
                acc[t] = __builtin_amdgcn_mfma_f32_16x16x32_bf16(ahi,  bmd, acc[t], 0,0,0);
                acc[t] = __builtin_amdgcn_mfma_f32_16x16x32_bf16(amid, bhi, acc[t], 0,0,0);
                acc[t] = __builtin_amdgcn_mfma_f32_16x16x32_bf16(ahi,  blo, acc[t], 0,0,0);
                acc[t] = __builtin_amdgcn_mfma_f32_16x16x32_bf16(amid, bmd, acc[t], 0,0,0);
                acc[t] = __builtin_amdgcn_mfma_f32_16x16x32_bf16(alo,  bhi, acc[t], 0,0,0);
            }
        }

        fn += __shfl_xor(fn, 16);
        fn += __shfl_xor(fn, 32);

        // C layout: col(n) = L&15, row(pixel) = q*4 + reg
        float vmin[4];
        #pragma unroll
        for (int r = 0; r < 4; r++) {
            float fnr = __shfl(fn, q*4 + r);
            float d0 = fnr + gn0 - 2.f*acc[0][r];
            float d1 = fnr + gn1 - 2.f*acc[1][r];
            float v = fminf(d0, d1);
            v = fminf(v, __shfl_xor(v, 1));
            v = fminf(v, __shfl_xor(v, 2));
            v = fminf(v, __shfl_xor(v, 4));
            v = fminf(v, __shfl_xor(v, 8));
            vmin[r] = v;
        }
        if (m < 4) {
            float v = (m==0) ? vmin[0] : (m==1) ? vmin[1] : (m==2) ? vmin[2] : vmin[3];
            if (!(v > 0.f)) v = 0.f;     // clamp negatives and -0.0
            uint32_t key = __float_as_uint(v);
            keys[(size_t)(b << 16) + p0 + q*4 + m] = key;
            atomicAdd(&h[(b << 16) + qbin_of(key)], 1u);   // spread bins: safe fused
        }
    }
}

// ---------------- K2: scan 65536 bins for RANK -> qbin T, within-bin rank r2 ----------------
__global__ __launch_bounds__(1024) void k_selq(const uint32_t* __restrict__ h,
                                               uint32_t* __restrict__ sm) {
    int b = blockIdx.x, t = threadIdx.x;   // 1024 threads, 64 bins each
    __shared__ uint32_t seg[1024];
    __shared__ uint32_t pre[1024];
    const uint4* h4 = (const uint4*)(h + (b << 16) + t*64);
    uint32_t s = 0;
    #pragma unroll
    for (int i = 0; i < 16; i++) { uint4 v = h4[i]; s += v.x + v.y + v.z + v.w; }
    seg[t] = s;
    __syncthreads();
    if (t == 0) { uint32_t c = 0; for (int i = 0; i < 1024; i++) { pre[i] = c; c += seg[i]; } }
    __syncthreads();
    uint32_t r = RANK;
    if (pre[t] <= r && r < pre[t] + seg[t]) {
        uint32_t c = pre[t];
        const uint32_t* hb = h + (b << 16) + t*64;
        for (int i = 0; i < 64; i++) {
            uint32_t hc = hb[i];
            if (r < c + hc) { sm[4 + b] = (uint32_t)(t*64 + i); sm[8 + b] = r - c; break; }
            c += hc;
        }
    }
}

// ---------------- K3: collect candidate keys in bin T (~5-15/batch) ----------------
__global__ __launch_bounds__(256) void k_collect(const uint32_t* __restrict__ keys,
        uint32_t* __restrict__ sm, uint32_t* __restrict__ cand) {
    int b = blockIdx.y;
    int p = blockIdx.x*256 + threadIdx.x;
    uint32_t k = keys[(b << 16) + p];
    if (qbin_of(k) == sm[4 + b]) {
        uint32_t pos = atomicAdd(&sm[b], 1u);
        if (pos < 65536u) cand[(b << 16) + pos] = k;
    }
}

// ---------------- K4: exact rank among candidates -> threshold key bits ----------------
__global__ void k_rank(const uint32_t* __restrict__ cand, uint32_t* __restrict__ sm) {
    int b = blockIdx.x, t = threadIdx.x;   // 256 threads
    uint32_t K = sm[b]; if (K > 65536u) K = 65536u;
    uint32_t r2 = sm[8 + b];
    const uint32_t* cb = cand + (b << 16);
    for (uint32_t i = t; i < K; i += 256) {
        uint32_t v = cb[i];
        uint32_t less = 0, eq = 0;
        for (uint32_t j = 0; j < K; j++) { uint32_t w = cb[j]; less += (w < v); eq += (w == v); }
        if (less <= r2 && r2 < less + eq) sm[12 + b] = v;   // all writers agree
    }
}

// ---------------- K5: init union-find parents from mask ----------------
__global__ __launch_bounds__(256) void k_initp(const uint32_t* __restrict__ keys,
        const uint32_t* __restrict__ sm, int* __restrict__ P) {
    int b = blockIdx.y;
    int p = blockIdx.x*256 + threadIdx.x;
    P[(b << 16) + p] = (keys[(b << 16) + p] >= sm[12 + b]) ? p : -1;
}

// ---------------- K6: union-find CCL (8-connected) ----------------
__device__ __forceinline__ int uf_find(int* P, int x) {
    while (true) {
        int p = P[x];
        if (p == x) return x;
        int gp = P[p];
        if (gp != p) P[x] = gp;   // path halving (benign race)
        x = gp;
    }
}
__device__ __forceinline__ void uf_unite(int* P, int a, int b) {
    while (true) {
        a = uf_find(P, a);
        b = uf_find(P, b);
        if (a == b) return;
        if (a > b) { int t = a; a = b; b = t; }
        int old = atomicCAS(&P[b], b, a);   // device-scope
        if (old == b) return;
        b = old;
    }
}
__global__ __launch_bounds__(256) void k_union(int* __restrict__ Pg) {
    int b = blockIdx.y;
    int p = blockIdx.x*256 + threadIdx.x;
    int* P = Pg + (b << 16);
    if (P[p] == -1) return;
    int y = p >> 8, x = p & 255;
    if (x > 0      && P[p-1]      != -1) uf_unite(P, p, p-1);
    if (y > 0) {
        if (          P[p-WW]     != -1) uf_unite(P, p, p-WW);
        if (x > 0  && P[p-WW-1]   != -1) uf_unite(P, p, p-WW-1);
        if (x < WW-1 && P[p-WW+1] != -1) uf_unite(P, p, p-WW+1);
    }
}

// ---------------- K7: merged pairs at centers + output ----------------
__global__ void k_pairs_fin(const int* __restrict__ centers, int* __restrict__ Pg,
                            float* __restrict__ out) {
    __shared__ int ids[BB*NN];
    __shared__ int total;
    int t = threadIdx.x;
    if (t == 0) total = 0;
    __syncthreads();
    if (t < BB*NN) {
        int b = t >> 5;
        int cy = centers[t*2 + 0];
        int cx = centers[t*2 + 1];
        int p = cy*WW + cx;
        const int* P = Pg + (b << 16);
        int id = P[p];
        if (id != -1) {
            int x = p;
            while (true) { int q = P[x]; if (q == x) break; x = q; }
            id = x;
        }
        ids[t] = id;
    }
    __syncthreads();
    int cnt = 0;
    if (t < BB*NN) {
        int b = t >> 5, n = t & 31;
        int id = ids[t];
        if (id != -1) for (int j = n+1; j < NN; j++) cnt += (ids[b*NN + j] == id);
    }
    if (cnt) atomicAdd(&total, cnt);
    __syncthreads();
    if (t == 0) out[0] = (float)total / TOTAL_PAIRS;
}

extern "C" void kernel_launch(void* const* d_in, const int* in_sizes, int n_in,
                              void* d_out, int out_size, void* d_ws, size_t ws_size,
                              hipStream_t stream) {
    const float* feat  = (const float*)d_in[0];
    const int* centers = (const int*)d_in[1];
    float* out         = (float*)d_out;
    char* ws           = (char*)d_ws;

    uint32_t* sm     = (uint32_t*)(ws + OFF_SM);
    uint32_t* h      = (uint32_t*)(ws + OFF_H);
    short*    gsplit = (short*)(ws + OFF_GSPLIT);
    float*    gnorm  = (float*)(ws + OFF_GN);
    uint32_t* keys   = (uint32_t*)(ws + OFF_KEYS);
    uint32_t* cand   = (uint32_t*)(ws + OFF_CAND);
    int*      Pg     = (int*)(ws + OFF_P);

    dim3 gridPix(NPIX/256, BB);
    dim3 gridMM(NPIX/256, BB);   // 256 px/block

    k_gather    <<<BB*NN, CC, 0, stream>>>(feat, centers, gsplit, gnorm, h, sm);
    k_d2mfma    <<<gridMM, 256, 0, stream>>>(feat, gsplit, gnorm, keys, h);
    k_selq      <<<BB, 1024, 0, stream>>>(h, sm);
    k_collect   <<<gridPix, 256, 0, stream>>>(keys, sm, cand);
    k_rank      <<<BB, 256, 0, stream>>>(cand, sm);
    k_initp     <<<gridPix, 256, 0, stream>>>(keys, sm, Pg);
    k_union     <<<gridPix, 256, 0, stream>>>(Pg);
    k_pairs_fin <<<1, 256, 0, stream>>>(centers, Pg, out);
}